// Round 1
// baseline (136.038 us; speedup 1.0000x reference)
//
#include <hip/hip_runtime.h>

// Bidirectional LSTM, B=16384 T=512 I=1 H=8, + final linear on [h_f(T-1), h_b(T-1)].
// Key insight: backward direction's state at time T-1 is its FIRST scan step ->
// only ONE backward LSTM step (on x[:,T-1]) is needed.
//
// Decomposition: 8 lanes per batch element. Lane j holds h[j], c[j] and computes
// gate rows {j, 8+j, 16+j, 24+j} of z = x*w_ih^T + h*w_hh^T + b (PyTorch gate
// order i,f,g,o). Recurrent weights live in 32 VGPRs per lane. h is broadcast
// within the 8-lane group each step via ds_swizzle (static bit-mode pattern).

#define LOG2E 1.4426950408889634f

// sigmoid(x) = 1/(1+exp2(-x*log2e)); exact limits at +-inf via v_exp/v_rcp.
__device__ __forceinline__ float fsig(float x) {
    float e = __builtin_amdgcn_exp2f(-x * LOG2E);
    return __builtin_amdgcn_rcpf(1.0f + e);
}
// tanh(x) = 1 - 2/(1+exp2(2x*log2e)); saturates correctly at +-inf.
__device__ __forceinline__ float ftanh(float x) {
    float e = __builtin_amdgcn_exp2f(x * (2.0f * LOG2E));
    return 1.0f - 2.0f * __builtin_amdgcn_rcpf(1.0f + e);
}

// Broadcast lane ((i & ~7) | k)'s value to all lanes i of each 8-lane group.
// ds_swizzle bit-mode: offset = (xor<<10) | (or<<5) | and ; src = (i & and | or) ^ xor
#define BCAST8(v, k) __int_as_float(__builtin_amdgcn_ds_swizzle(__float_as_int(v), (((k) << 5) | 0x18)))

__device__ __forceinline__ void lstm_step(float xt, float& h, float& c,
    const float* wi, const float* wf, const float* wg, const float* wo,
    float wxi, float wxf, float wxg, float wxo,
    float bi, float bff, float bg, float bo)
{
    float hk[8];
    hk[0] = BCAST8(h, 0); hk[1] = BCAST8(h, 1);
    hk[2] = BCAST8(h, 2); hk[3] = BCAST8(h, 3);
    hk[4] = BCAST8(h, 4); hk[5] = BCAST8(h, 5);
    hk[6] = BCAST8(h, 6); hk[7] = BCAST8(h, 7);
    float zi = fmaf(xt, wxi, bi);
    float zf = fmaf(xt, wxf, bff);
    float zg = fmaf(xt, wxg, bg);
    float zo = fmaf(xt, wxo, bo);
#pragma unroll
    for (int k = 0; k < 8; ++k) {
        zi = fmaf(hk[k], wi[k], zi);
        zf = fmaf(hk[k], wf[k], zf);
        zg = fmaf(hk[k], wg[k], zg);
        zo = fmaf(hk[k], wo[k], zo);
    }
    float si = fsig(zi);
    float sf = fsig(zf);
    float tg = ftanh(zg);
    float so = fsig(zo);
    c = fmaf(sf, c, si * tg);
    h = so * ftanh(c);
}

__global__ __launch_bounds__(256, 2) void bilstm_kernel(
    const float* __restrict__ x, const float* __restrict__ h0, const float* __restrict__ c0,
    const float* __restrict__ w_ih_f, const float* __restrict__ w_hh_f, const float* __restrict__ b_f,
    const float* __restrict__ w_ih_b, const float* __restrict__ w_hh_b, const float* __restrict__ b_b,
    const float* __restrict__ w_lin, const float* __restrict__ b_lin,
    float* __restrict__ out, int B, int T)
{
    int tid = blockIdx.x * 256 + threadIdx.x;
    int b = tid >> 3;
    int j = tid & 7;
    if (b >= B) return;

    // ---- forward-direction per-lane weights (rows j, 8+j, 16+j, 24+j) ----
    float wi[8], wf[8], wg[8], wo[8];
    {
        const float4* whh = (const float4*)w_hh_f;
        *(float4*)&wi[0] = whh[2 * j];          *(float4*)&wi[4] = whh[2 * j + 1];
        *(float4*)&wf[0] = whh[2 * (8 + j)];    *(float4*)&wf[4] = whh[2 * (8 + j) + 1];
        *(float4*)&wg[0] = whh[2 * (16 + j)];   *(float4*)&wg[4] = whh[2 * (16 + j) + 1];
        *(float4*)&wo[0] = whh[2 * (24 + j)];   *(float4*)&wo[4] = whh[2 * (24 + j) + 1];
    }
    float wxi = w_ih_f[j], wxf = w_ih_f[8 + j], wxg = w_ih_f[16 + j], wxo = w_ih_f[24 + j];
    float bi = b_f[j], bff = b_f[8 + j], bg = b_f[16 + j], bo = b_f[24 + j];

    float h = h0[(size_t)b * 8 + j];
    float c = c0[(size_t)b * 8 + j];

    // ---- forward scan over T steps ----
    const float4* xr = (const float4*)(x + (size_t)b * T);
    int nT4 = T >> 2;
    for (int t4 = 0; t4 < nT4; ++t4) {
        float4 xv = xr[t4];
        float xs[4] = {xv.x, xv.y, xv.z, xv.w};
#pragma unroll
        for (int u = 0; u < 4; ++u) {
            lstm_step(xs[u], h, c, wi, wf, wg, wo, wxi, wxf, wxg, wxo, bi, bff, bg, bo);
        }
    }

    // ---- backward direction: exactly ONE step on x[:, T-1] ----
    float vi[8], vf[8], vg[8], vo[8];
    {
        const float4* whh = (const float4*)w_hh_b;
        *(float4*)&vi[0] = whh[2 * j];          *(float4*)&vi[4] = whh[2 * j + 1];
        *(float4*)&vf[0] = whh[2 * (8 + j)];    *(float4*)&vf[4] = whh[2 * (8 + j) + 1];
        *(float4*)&vg[0] = whh[2 * (16 + j)];   *(float4*)&vg[4] = whh[2 * (16 + j) + 1];
        *(float4*)&vo[0] = whh[2 * (24 + j)];   *(float4*)&vo[4] = whh[2 * (24 + j) + 1];
    }
    float vxi = w_ih_b[j], vxf = w_ih_b[8 + j], vxg = w_ih_b[16 + j], vxo = w_ih_b[24 + j];
    float ci = b_b[j], cf = b_b[8 + j], cg = b_b[16 + j], co = b_b[24 + j];

    float hb = h0[(size_t)B * 8 + (size_t)b * 8 + j];
    float cb = c0[(size_t)B * 8 + (size_t)b * 8 + j];
    float xlast = x[(size_t)b * T + (T - 1)];
    lstm_step(xlast, hb, cb, vi, vf, vg, vo, vxi, vxf, vxg, vxo, ci, cf, cg, co);

    // ---- final linear: out[b] = sum_j h[j]*w_lin[j] + hb[j]*w_lin[8+j] + b_lin ----
    float part = fmaf(h, w_lin[j], hb * w_lin[8 + j]);
    part += __shfl_xor(part, 1, 8);
    part += __shfl_xor(part, 2, 8);
    part += __shfl_xor(part, 4, 8);
    if (j == 0) out[b] = part + b_lin[0];
}

extern "C" void kernel_launch(void* const* d_in, const int* in_sizes, int n_in,
                              void* d_out, int out_size, void* d_ws, size_t ws_size,
                              hipStream_t stream)
{
    const float* x      = (const float*)d_in[0];
    const float* h0     = (const float*)d_in[1];
    const float* c0     = (const float*)d_in[2];
    const float* w_ih_f = (const float*)d_in[3];
    const float* w_hh_f = (const float*)d_in[4];
    const float* b_f    = (const float*)d_in[5];
    const float* w_ih_b = (const float*)d_in[6];
    const float* w_hh_b = (const float*)d_in[7];
    const float* b_b    = (const float*)d_in[8];
    const float* w_lin  = (const float*)d_in[9];
    const float* b_lin  = (const float*)d_in[10];
    float* out = (float*)d_out;

    int B = in_sizes[1] / 16;   // h0: (2, B, 8)
    int T = in_sizes[0] / B;    // x:  (B, T, 1)

    int threads = B * 8;
    dim3 block(256);
    dim3 grid((threads + 255) / 256);
    hipLaunchKernelGGL(bilstm_kernel, grid, block, 0, stream,
                       x, h0, c0, w_ih_f, w_hh_f, b_f, w_ih_b, w_hh_b, b_b,
                       w_lin, b_lin, out, B, T);
}